// Round 9
// baseline (536.122 us; speedup 1.0000x reference)
//
#include <hip/hip_runtime.h>
#include <stdint.h>
#include <stddef.h>

using f16 = _Float16;
typedef __attribute__((ext_vector_type(8))) _Float16 f16x8;
typedef __attribute__((ext_vector_type(4))) float f32x4;

constexpr int BM = 128, BN = 128;

// ---------------------------------------------------------------------------
// Transpose X [D][NT] fp32 -> Xt [NT][D] fp32 + fp16.
__global__ __launch_bounds__(256)
void transpose_x(const float* __restrict__ in, float* __restrict__ outF,
                 f16* __restrict__ outH, int R, int C) {
    __shared__ float tile[32][33];
    const int tx = threadIdx.x & 31, ty = threadIdx.x >> 5;
    const int c0 = blockIdx.x * 32, r0 = blockIdx.y * 32;
#pragma unroll
    for (int j = 0; j < 4; j++)
        tile[ty + j * 8][tx] = in[(size_t)(r0 + ty + j * 8) * C + c0 + tx];
    __syncthreads();
#pragma unroll
    for (int j = 0; j < 4; j++) {
        float v = tile[tx][ty + j * 8];
        size_t idx = (size_t)(c0 + ty + j * 8) * R + r0 + tx;
        outF[idx] = v;
        outH[idx] = (f16)v;
    }
}

// Weight prep: z<3 -> fp16 convert (Wq, Wk, Wv); z>=3 -> fp16 transpose.
__global__ __launch_bounds__(256)
void prep_w(const float* __restrict__ w0, const float* __restrict__ w1,
            const float* __restrict__ w2, const float* __restrict__ w3,
            const float* __restrict__ w4, const float* __restrict__ w5,
            f16* o0, f16* o1, f16* o2, f16* o3, f16* o4, f16* o5, int D) {
    const int z = blockIdx.z;
    const float* in = z == 0 ? w0 : z == 1 ? w1 : z == 2 ? w2 : z == 3 ? w3 : z == 4 ? w4 : w5;
    f16* out = z == 0 ? o0 : z == 1 ? o1 : z == 2 ? o2 : z == 3 ? o3 : z == 4 ? o4 : o5;
    const int tx = threadIdx.x & 31, ty = threadIdx.x >> 5;
    const int c0 = blockIdx.x * 32, r0 = blockIdx.y * 32;
    if (z < 3) {
#pragma unroll
        for (int j = 0; j < 4; j++) {
            size_t idx = (size_t)(r0 + ty + j * 8) * D + c0 + tx;
            out[idx] = (f16)in[idx];
        }
    } else {
        __shared__ float tile[32][33];
#pragma unroll
        for (int j = 0; j < 4; j++)
            tile[ty + j * 8][tx] = in[(size_t)(r0 + ty + j * 8) * D + c0 + tx];
        __syncthreads();
#pragma unroll
        for (int j = 0; j < 4; j++)
            out[(size_t)(c0 + ty + j * 8) * D + r0 + tx] = (f16)tile[tx][ty + j * 8];
    }
}

// ---------------------------------------------------------------------------
// Causal softmax IN-PLACE: fp32 S row -> fp16 A in same memory (pitch 2N).
__global__ __launch_bounds__(256)
void softmax_causal_inplace(float* __restrict__ S, int N) {
    const int row = blockIdx.x;
    const int len = row + 1;
    float* s = S + (size_t)row * N;
    f16* a = (f16*)s;
    __shared__ float red[256];
    const int t = threadIdx.x;

    float v[16];
    float mx = -1e30f;
#pragma unroll
    for (int j = 0; j < 16; j++) {
        int c = t + j * 256;
        if (c < len) { v[j] = s[c]; mx = fmaxf(mx, v[j]); }
    }
    red[t] = mx; __syncthreads();
    for (int o = 128; o > 0; o >>= 1) { if (t < o) red[t] = fmaxf(red[t], red[t + o]); __syncthreads(); }
    mx = red[0]; __syncthreads();

    float sum = 0.f;
#pragma unroll
    for (int j = 0; j < 16; j++) {
        int c = t + j * 256;
        if (c < len) sum += __expf(v[j] - mx);
    }
    red[t] = sum; __syncthreads();
    for (int o = 128; o > 0; o >>= 1) { if (t < o) red[t] += red[t + o]; __syncthreads(); }
    const float inv = 1.0f / red[0];
#pragma unroll
    for (int j = 0; j < 16; j++) {
        int c = t + j * 256;
        a[c] = (f16)((c < len) ? __expf(v[j] - mx) * inv : 0.0f);
    }
}

// ---------------------------------------------------------------------------
// Direct-global fragment loads (no LDS, no barriers). The global access
// pattern of a fragment load (16 rows x 64 B per wave instruction) is
// identical to the old global_load_lds staging — same coalescing, but the
// K-loop becomes per-wave pipelined (compiler emits vmcnt(N), never 0) and
// the 8 waves/CU free-run instead of locking on a block barrier.

// 128x128 body helpers: 4 waves in 2x2; per wave 8 A-frags + 8 B-frags / K64.
__device__ __forceinline__ void ld16(const f16* pa, const f16* pb, size_t sa,
                                     size_t sb, int k, f16x8 (&a)[8], f16x8 (&b)[8]) {
#pragma unroll
    for (int kk = 0; kk < 2; kk++)
#pragma unroll
        for (int i = 0; i < 4; i++) {
            a[i + 4 * kk] = *(const f16x8*)(pa + i * sa + k + kk * 32);
            b[i + 4 * kk] = *(const f16x8*)(pb + i * sb + k + kk * 32);
        }
}
__device__ __forceinline__ void mm16(const f16x8 (&a)[8], const f16x8 (&b)[8],
                                     f32x4 (&acc)[4][4]) {
#pragma unroll
    for (int kk = 0; kk < 2; kk++)
#pragma unroll
        for (int i = 0; i < 4; i++)
#pragma unroll
            for (int j = 0; j < 4; j++)
                acc[i][j] = __builtin_amdgcn_mfma_f32_16x16x32_f16(
                    a[i + 4 * kk], b[j + 4 * kk], acc[i][j], 0, 0, 0);
}

// MODE 0: Ch = f16(acc);  MODE 1: Cf = acc.  K must be a multiple of 128.
template <int MODE>
__device__ __forceinline__ void plain_body(
    const f16* __restrict__ A, const f16* __restrict__ B,
    float* __restrict__ Cf, f16* __restrict__ Ch,
    int m0, int n0, int N, int K, int lda) {
    const int lane = threadIdx.x & 63, wave = threadIdx.x >> 6;
    const int wm = (wave >> 1) * 64, wn = (wave & 1) * 64;
    const int lm = lane & 15, lq = lane >> 4;

    const f16* pa = A + (size_t)(m0 + wm + lm) * lda + lq * 8;
    const f16* pb = B + (size_t)(n0 + wn + lm) * (size_t)K + lq * 8;
    const size_t sa = (size_t)16 * lda, sb = (size_t)16 * K;

    f32x4 acc[4][4] = {};
    f16x8 a0[8], b0[8], a1[8], b1[8];

    ld16(pa, pb, sa, sb, 0, a0, b0);
    for (int k0 = 0; k0 < K; k0 += 128) {
        ld16(pa, pb, sa, sb, k0 + 64, a1, b1);
        mm16(a0, b0, acc);
        const int k2 = (k0 + 128 < K) ? k0 + 128 : 0;  // clamped prefetch
        ld16(pa, pb, sa, sb, k2, a0, b0);
        mm16(a1, b1, acc);
    }

    // C/D layout: col = lane&15, row = (lane>>4)*4 + reg.
#pragma unroll
    for (int i = 0; i < 4; i++) {
        const int row = m0 + wm + i * 16 + lq * 4;
#pragma unroll
        for (int j = 0; j < 4; j++) {
            const int col = n0 + wn + j * 16 + lm;
            f32x4 v = acc[i][j];
#pragma unroll
            for (int r = 0; r < 4; r++) {
                if (MODE == 0) Ch[(size_t)(row + r) * N + col] = (f16)v[r];
                else           Cf[(size_t)(row + r) * N + col] = v[r];
            }
        }
    }
}

// 128x64 body helpers: 4 waves stacked on M; per wave 4 A-frags + 8 B-frags.
__device__ __forceinline__ void ld12(const f16* pa, const f16* pb, size_t sa,
                                     size_t sb, int k, f16x8 (&a)[4], f16x8 (&b)[8]) {
#pragma unroll
    for (int kk = 0; kk < 2; kk++) {
#pragma unroll
        for (int i = 0; i < 2; i++)
            a[i + 2 * kk] = *(const f16x8*)(pa + i * sa + k + kk * 32);
#pragma unroll
        for (int j = 0; j < 4; j++)
            b[j + 4 * kk] = *(const f16x8*)(pb + j * sb + k + kk * 32);
    }
}
__device__ __forceinline__ void mm8(const f16x8 (&a)[4], const f16x8 (&b)[8],
                                    f32x4 (&acc)[2][4]) {
#pragma unroll
    for (int kk = 0; kk < 2; kk++)
#pragma unroll
        for (int i = 0; i < 2; i++)
#pragma unroll
            for (int j = 0; j < 4; j++)
                acc[i][j] = __builtin_amdgcn_mfma_f32_16x16x32_f16(
                    a[i + 2 * kk], b[j + 4 * kk], acc[i][j], 0, 0, 0);
}

// MODE 2: Cf = acc + resid; Ch = f16(Cf)
// MODE 3: Ch = f16(relu(acc))
// MODE 4: Cf[col*M + row] = acc + resid[row*N + col]  (transposed store)
// Keff must be a multiple of 128.
template <int MODE>
__device__ __forceinline__ void narrow_body(
    const f16* __restrict__ A, const f16* __restrict__ B,
    float* __restrict__ Cf, f16* __restrict__ Ch, const float* __restrict__ resid,
    int m0, int n0, int M, int N, int K, int lda, int Keff) {
    const int lane = threadIdx.x & 63, wave = threadIdx.x >> 6;
    const int lm = lane & 15, lq = lane >> 4;

    const f16* pa = A + (size_t)(m0 + wave * 32 + lm) * lda + lq * 8;
    const f16* pb = B + (size_t)(n0 + lm) * (size_t)K + lq * 8;
    const size_t sa = (size_t)16 * lda, sb = (size_t)16 * K;

    f32x4 acc[2][4] = {};
    f16x8 a0[4], b0[8], a1[4], b1[8];

    ld12(pa, pb, sa, sb, 0, a0, b0);
    for (int k0 = 0; k0 < Keff; k0 += 128) {
        ld12(pa, pb, sa, sb, k0 + 64, a1, b1);
        mm8(a0, b0, acc);
        const int k2 = (k0 + 128 < Keff) ? k0 + 128 : 0;
        ld12(pa, pb, sa, sb, k2, a0, b0);
        mm8(a1, b1, acc);
    }

#pragma unroll
    for (int i = 0; i < 2; i++) {
        const int row = m0 + wave * 32 + i * 16 + lq * 4;
#pragma unroll
        for (int j = 0; j < 4; j++) {
            const int col = n0 + j * 16 + lm;
            f32x4 v = acc[i][j];
#pragma unroll
            for (int r = 0; r < 4; r++) {
                if (MODE == 2) {
                    float o = v[r] + resid[(size_t)(row + r) * N + col];
                    Cf[(size_t)(row + r) * N + col] = o;
                    Ch[(size_t)(row + r) * N + col] = (f16)o;
                } else if (MODE == 3) {
                    Ch[(size_t)(row + r) * N + col] = (f16)fmaxf(v[r], 0.0f);
                } else {
                    float o = v[r] + resid[(size_t)(row + r) * N + col];
                    Cf[(size_t)col * M + (row + r)] = o;
                }
            }
        }
    }
}

// ---------------------------------------------------------------------------
// Fused: GT = Wk*Wq^T ++ HT = Wo^T*Wv^T, both [1024^3], 128 blocks.
__global__ __launch_bounds__(256, 2)
void tiny_pair(const f16* Wkh, const f16* Wqh, f16* GT,
               const f16* Wot, const f16* Wvh, f16* HT) {
    const int x = blockIdx.x;
    if (x < 64) {
        plain_body<0>(Wkh, Wqh, nullptr, GT,
                      (x >> 3) * BM, (x & 7) * BN, 1024, 1024, 1024);
    } else {
        const int r = x - 64;
        plain_body<0>(Wot, Wvh, nullptr, HT,
                      (r >> 3) * BM, (r & 7) * BN, 1024, 1024, 1024);
    }
}

// Fused: Q' = Xt*GT^T [4096,1024,1024] ++ RHt = HT*Xt^T [1024,4096,1024].
// XCD-affinity: blocks sharing an Xt stripe land on one blockIdx%8 residue.
__global__ __launch_bounds__(256, 2)
void mid_pair(const f16* Xth, const f16* GT, f16* Qp,
              const f16* HT, f16* RHt) {
    const int b = blockIdx.x;
    const int x = b & 7;
    if (b < 256) {
        const int s = b >> 3;  // 0..31
        const int m = x + 8 * (s >> 3), n = s & 7;
        plain_body<0>(Xth, GT, nullptr, Qp, m * BM, n * BN, 1024, 1024, 1024);
    } else {
        const int s = (b - 256) >> 3;  // 0..31
        const int n = x + 8 * (s >> 3), m = s & 7;
        plain_body<0>(HT, Xth, nullptr, RHt, m * BM, n * BN, 4096, 1024, 1024);
    }
}

// Scores over lower triangle: S = Q'*Xt^T, fp32 out, 528 blocks.
// XCD-affinity + balance: residue x owns m in {31-x, 16+x, 15-x, x}.
__global__ __launch_bounds__(256, 2)
void scores_tri(const f16* Qp, const f16* Xth, float* S) {
    const int x = blockIdx.x & 7, s = blockIdx.x >> 3;  // s in 0..65
    const int c0 = 32 - x, c1 = 17 + x, c2 = 16 - x;
    int m, n;
    if (s < c0)                { m = 31 - x; n = s; }
    else if (s < c0 + c1)      { m = 16 + x; n = s - c0; }
    else if (s < c0 + c1 + c2) { m = 15 - x; n = s - c0 - c1; }
    else                       { m = x;      n = s - c0 - c1 - c2; }
    plain_body<1>(Qp, Xth, S, nullptr, m * BM, n * BN, 4096, 1024, 1024);
}

// Standalone narrow GEMM, 1D grid of 512 (M=4096, N=1024).
// SWZ 0: uniform-K, residue x owns m = x + 8*(s>>4).
// SWZ 1: causal-K balanced, residue x owns m in {31-x, 16+x, 15-x, x}.
template <int MODE, bool CAUSAL_K, int SWZ>
__global__ __launch_bounds__(256, 2)
void gemm_narrow(const f16* __restrict__ A, const f16* __restrict__ B,
                 float* __restrict__ Cf, f16* __restrict__ Ch,
                 const float* __restrict__ resid, int M, int N, int K, int lda) {
    const int x = blockIdx.x & 7, s = blockIdx.x >> 3;  // s in 0..63
    const int q = s >> 4, n = s & 15;
    int m;
    if (SWZ == 1) m = (q == 0) ? 31 - x : (q == 1) ? 16 + x : (q == 2) ? 15 - x : x;
    else          m = x + 8 * q;
    const int m0 = m * BM, n0 = n * 64;
    const int Keff = CAUSAL_K ? (K < m0 + BM ? K : m0 + BM) : K;
    narrow_body<MODE>(A, B, Cf, Ch, resid, m0, n0, M, N, K, lda, Keff);
}

// ---------------------------------------------------------------------------
extern "C" void kernel_launch(void* const* d_in, const int* in_sizes, int n_in,
                              void* d_out, int out_size, void* d_ws, size_t ws_size,
                              hipStream_t stream) {
    const int D = 1024, NT = 4096;
    const float* X = (const float*)d_in[0];
    const float* W[6] = {(const float*)d_in[1], (const float*)d_in[2],
                         (const float*)d_in[3], (const float*)d_in[4],
                         (const float*)d_in[5], (const float*)d_in[6]};
    char* ws = (char*)d_ws;
    auto MB = [](size_t x) { return x << 20; };

    // Workspace (144 MB peak):
    float* Xtf  = (float*)(ws + MB(0));    // [NT][D] fp32 residual
    f16*   Xth  = (f16*)(ws + MB(16));     // [NT][D]
    f16*   Wqh  = (f16*)(ws + MB(24));
    f16*   Wkh  = (f16*)(ws + MB(26));
    f16*   Wvh  = (f16*)(ws + MB(28));
    f16*   Wot  = (f16*)(ws + MB(30));
    f16*   W4t  = (f16*)(ws + MB(32));
    f16*   W5t  = (f16*)(ws + MB(34));
    f16*   GT   = (f16*)(ws + MB(36));     // [D][D]
    f16*   HT   = (f16*)(ws + MB(38));     // [D][D]
    f16*   Qp   = (f16*)(ws + MB(40));     // [NT][D] (dead after scores)
    float* S    = (float*)(ws + MB(48));   // [NT][NT] fp32 -> A f16 in-place
    f16*   RHt  = (f16*)(ws + MB(112));    // [D][NT]
    float* Y1f  = (float*)(ws + MB(120));  // [NT][D] fp32
    f16*   Y1h  = (f16*)(ws + MB(136));    // [NT][D]
    f16*   hb   = (f16*)(ws + MB(40));     // over Qp (dead)
    float* outF = (float*)d_out;           // [D][NT]

    // 1. Prep.
    transpose_x<<<dim3(NT / 32, D / 32), 256, 0, stream>>>(X, Xtf, Xth, D, NT);
    prep_w<<<dim3(D / 32, D / 32, 6), 256, 0, stream>>>(
        W[0], W[1], W[2], W[3], W[4], W[5], Wqh, Wkh, Wvh, Wot, W4t, W5t, D);

    // 2. GT = Wk*Wq^T ++ HT = Wo^T*Wv^T.
    tiny_pair<<<128, 256, 0, stream>>>(Wkh, Wqh, GT, Wot, Wvh, HT);

    // 3. Q' = Xt*G ++ RHt = HT*Xt^T.
    mid_pair<<<512, 256, 0, stream>>>(Xth, GT, Qp, HT, RHt);

    // 4. Scores (lower triangle, fp32).
    scores_tri<<<528, 256, 0, stream>>>(Qp, Xth, S);

    // 5. Softmax in-place (A f16, pitch 2*NT).
    softmax_causal_inplace<<<NT, 256, 0, stream>>>(S, NT);
    f16* Ab = (f16*)S;

    // 6. Y1 = Xt + A@RH (causal-K truncation, XCD-affine + balanced).
    gemm_narrow<2, true, 1><<<512, 256, 0, stream>>>(
        Ab, RHt, Y1f, Y1h, Xtf, NT, D, NT, 2 * NT);

    // 7. h = relu(Y1 @ mlp_in).
    gemm_narrow<3, false, 0><<<512, 256, 0, stream>>>(
        Y1h, W4t, nullptr, hb, nullptr, NT, D, D, D);

    // 8. out = (Y1 + h @ mlp_out)^T.
    gemm_narrow<4, false, 0><<<512, 256, 0, stream>>>(
        hb, W5t, outF, nullptr, Y1f, NT, D, D, D);
}

// Round 10
// 267.881 us; speedup vs baseline: 2.0013x; 2.0013x over previous
//
#include <hip/hip_runtime.h>
#include <stdint.h>
#include <stddef.h>

using f16 = _Float16;
typedef __attribute__((ext_vector_type(8))) _Float16 f16x8;
typedef __attribute__((ext_vector_type(4))) float f32x4;

// ---------------------------------------------------------------------------
__device__ __forceinline__ void async_copy16(const f16* g, f16* l) {
    __builtin_amdgcn_global_load_lds(
        (const __attribute__((address_space(1))) void*)g,
        (__attribute__((address_space(3))) void*)l, 16, 0, 0);
}

// ---------------------------------------------------------------------------
// Transpose X [D][NT] fp32 -> Xt [NT][D] fp32 + fp16.
__global__ __launch_bounds__(256)
void transpose_x(const float* __restrict__ in, float* __restrict__ outF,
                 f16* __restrict__ outH, int R, int C) {
    __shared__ float tile[32][33];
    const int tx = threadIdx.x & 31, ty = threadIdx.x >> 5;
    const int c0 = blockIdx.x * 32, r0 = blockIdx.y * 32;
#pragma unroll
    for (int j = 0; j < 4; j++)
        tile[ty + j * 8][tx] = in[(size_t)(r0 + ty + j * 8) * C + c0 + tx];
    __syncthreads();
#pragma unroll
    for (int j = 0; j < 4; j++) {
        float v = tile[tx][ty + j * 8];
        size_t idx = (size_t)(c0 + ty + j * 8) * R + r0 + tx;
        outF[idx] = v;
        outH[idx] = (f16)v;
    }
}

// Weight prep: z<3 -> fp16 convert (Wq, Wk, Wv); z>=3 -> fp16 transpose.
__global__ __launch_bounds__(256)
void prep_w(const float* __restrict__ w0, const float* __restrict__ w1,
            const float* __restrict__ w2, const float* __restrict__ w3,
            const float* __restrict__ w4, const float* __restrict__ w5,
            f16* o0, f16* o1, f16* o2, f16* o3, f16* o4, f16* o5, int D) {
    const int z = blockIdx.z;
    const float* in = z == 0 ? w0 : z == 1 ? w1 : z == 2 ? w2 : z == 3 ? w3 : z == 4 ? w4 : w5;
    f16* out = z == 0 ? o0 : z == 1 ? o1 : z == 2 ? o2 : z == 3 ? o3 : z == 4 ? o4 : o5;
    const int tx = threadIdx.x & 31, ty = threadIdx.x >> 5;
    const int c0 = blockIdx.x * 32, r0 = blockIdx.y * 32;
    if (z < 3) {
#pragma unroll
        for (int j = 0; j < 4; j++) {
            size_t idx = (size_t)(r0 + ty + j * 8) * D + c0 + tx;
            out[idx] = (f16)in[idx];
        }
    } else {
        __shared__ float tile[32][33];
#pragma unroll
        for (int j = 0; j < 4; j++)
            tile[ty + j * 8][tx] = in[(size_t)(r0 + ty + j * 8) * D + c0 + tx];
        __syncthreads();
#pragma unroll
        for (int j = 0; j < 4; j++)
            out[(size_t)(c0 + ty + j * 8) * D + r0 + tx] = (f16)tile[tx][ty + j * 8];
    }
}

// ---------------------------------------------------------------------------
// Causal softmax IN-PLACE: fp32 S row -> fp16 A in same memory (pitch 2N).
__global__ __launch_bounds__(256)
void softmax_causal_inplace(float* __restrict__ S, int N) {
    const int row = blockIdx.x;
    const int len = row + 1;
    float* s = S + (size_t)row * N;
    f16* a = (f16*)s;
    __shared__ float red[256];
    const int t = threadIdx.x;

    float v[16];
    float mx = -1e30f;
#pragma unroll
    for (int j = 0; j < 16; j++) {
        int c = t + j * 256;
        if (c < len) { v[j] = s[c]; mx = fmaxf(mx, v[j]); }
    }
    red[t] = mx; __syncthreads();
    for (int o = 128; o > 0; o >>= 1) { if (t < o) red[t] = fmaxf(red[t], red[t + o]); __syncthreads(); }
    mx = red[0]; __syncthreads();

    float sum = 0.f;
#pragma unroll
    for (int j = 0; j < 16; j++) {
        int c = t + j * 256;
        if (c < len) sum += __expf(v[j] - mx);
    }
    red[t] = sum; __syncthreads();
    for (int o = 128; o > 0; o >>= 1) { if (t < o) red[t] += red[t + o]; __syncthreads(); }
    const float inv = 1.0f / red[0];
#pragma unroll
    for (int j = 0; j < 16; j++) {
        int c = t + j * 256;
        a[c] = (f16)((c < len) ? __expf(v[j] - mx) * inv : 0.0f);
    }
}

// ---------------------------------------------------------------------------
// 64x64x64 fp16 GEMM body (R8-proven global_load_lds staging, small tile for
// TLP: 16 KB LDS + <=128 VGPR -> 4 blocks/CU, 16 waves/CU; a barrier drain
// stalls only 1/4 of the CU's waves). 4 waves in 2x2, each 32x32 (2x2 MFMA
// tiles). LDS per operand: [2 k-halves][64][32].
// MODE 0: Ch = f16(acc)
// MODE 1: Cf = acc
// MODE 2: Cf = acc + resid; Ch = f16(Cf)
// MODE 3: Ch = f16(relu(acc))
// MODE 4: Cf[col*M + row] = acc + resid[row*N + col]  (transposed store)
template <int MODE>
__device__ __forceinline__ void body64(
    f16* lA, f16* lB, const f16* __restrict__ A, const f16* __restrict__ B,
    float* __restrict__ Cf, f16* __restrict__ Ch, const float* __restrict__ resid,
    int m0, int n0, int M, int N, int K, int lda, int Keff) {
    const int t = threadIdx.x;
    const int lane = t & 63, wave = t >> 6;
    const int wm = (wave >> 1) * 32, wn = (wave & 1) * 32;
    const int lm = lane & 15, lq = lane >> 4;
    const int sr = t >> 2, sc = (t & 3) * 8;   // 64 rows x 32 cols per k-half

    f32x4 acc[2][2] = {};

    for (int k0 = 0; k0 < Keff; k0 += 64) {
#pragma unroll
        for (int r = 0; r < 2; r++)
            async_copy16(A + (size_t)(m0 + sr) * lda + k0 + r * 32 + sc,
                         lA + r * 2048 + t * 8);
#pragma unroll
        for (int r = 0; r < 2; r++)
            async_copy16(B + (size_t)(n0 + sr) * K + k0 + r * 32 + sc,
                         lB + r * 2048 + t * 8);
        __syncthreads();

#pragma unroll
        for (int kk = 0; kk < 2; kk++) {
            f16x8 af[2], bf[2];
#pragma unroll
            for (int i = 0; i < 2; i++)
                af[i] = *(const f16x8*)&lA[kk * 2048 + (wm + i * 16 + lm) * 32 + lq * 8];
#pragma unroll
            for (int j = 0; j < 2; j++)
                bf[j] = *(const f16x8*)&lB[kk * 2048 + (wn + j * 16 + lm) * 32 + lq * 8];
#pragma unroll
            for (int i = 0; i < 2; i++)
#pragma unroll
                for (int j = 0; j < 2; j++)
                    acc[i][j] = __builtin_amdgcn_mfma_f32_16x16x32_f16(
                        af[i], bf[j], acc[i][j], 0, 0, 0);
        }
        __syncthreads();
    }

    // C/D layout: col = lane&15, row = (lane>>4)*4 + reg.
#pragma unroll
    for (int i = 0; i < 2; i++) {
        const int row = m0 + wm + i * 16 + lq * 4;
#pragma unroll
        for (int j = 0; j < 2; j++) {
            const int col = n0 + wn + j * 16 + lm;
            f32x4 v = acc[i][j];
#pragma unroll
            for (int r = 0; r < 4; r++) {
                if (MODE == 0) {
                    Ch[(size_t)(row + r) * N + col] = (f16)v[r];
                } else if (MODE == 1) {
                    Cf[(size_t)(row + r) * N + col] = v[r];
                } else if (MODE == 2) {
                    float o = v[r] + resid[(size_t)(row + r) * N + col];
                    Cf[(size_t)(row + r) * N + col] = o;
                    Ch[(size_t)(row + r) * N + col] = (f16)o;
                } else if (MODE == 3) {
                    Ch[(size_t)(row + r) * N + col] = (f16)fmaxf(v[r], 0.0f);
                } else {
                    float o = v[r] + resid[(size_t)(row + r) * N + col];
                    Cf[(size_t)col * M + (row + r)] = o;
                }
            }
        }
    }
}

// ---------------------------------------------------------------------------
// Fused: GT = Wk*Wq^T ++ HT = Wo^T*Wv^T, both [1024^3]. 512 blocks (256+256).
__global__ __launch_bounds__(256, 4)
void tiny_pair(const f16* Wkh, const f16* Wqh, f16* GT,
               const f16* Wot, const f16* Wvh, f16* HT) {
    __shared__ alignas(16) f16 smem[8192];
    const int b = blockIdx.x;
    if (b < 256)
        body64<0>(smem, smem + 4096, Wkh, Wqh, nullptr, GT, nullptr,
                  (b >> 4) * 64, (b & 15) * 64, 1024, 1024, 1024, 1024, 1024);
    else {
        const int r = b - 256;
        body64<0>(smem, smem + 4096, Wot, Wvh, nullptr, HT, nullptr,
                  (r >> 4) * 64, (r & 15) * 64, 1024, 1024, 1024, 1024, 1024);
    }
}

// Fused: Q' = Xt*GT^T [4096,1024,1024] ++ RHt = HT*Xt^T [1024,4096,1024].
// 2048 blocks. XCD-affinity: blocks sharing an Xt stripe share blockIdx%8.
__global__ __launch_bounds__(256, 4)
void mid_pair(const f16* Xth, const f16* GT, f16* Qp,
              const f16* HT, f16* RHt) {
    __shared__ alignas(16) f16 smem[8192];
    const int x = blockIdx.x & 7;
    int s = blockIdx.x >> 3;  // 0..255
    if (s < 128) {
        const int m = x + 8 * (s >> 4), n = s & 15;  // A-stripe affinity
        body64<0>(smem, smem + 4096, Xth, GT, nullptr, Qp, nullptr,
                  m * 64, n * 64, 4096, 1024, 1024, 1024, 1024);
    } else {
        s -= 128;
        const int n = x + 8 * (s >> 4), m = s & 15;  // B(Xth)-stripe affinity
        body64<0>(smem, smem + 4096, HT, Xth, nullptr, RHt, nullptr,
                  m * 64, n * 64, 1024, 4096, 1024, 1024, 1024);
    }
}

// Scores over lower triangle: S = Q'*Xt^T, fp32 out. 2080 blocks.
// Residue x owns m = 8q + (q odd ? 7-x : x) for q=7..0 (largest-K first) —
// exactly 260 K64-steps per residue (uniform) + A-stripe L2 affinity.
__global__ __launch_bounds__(256, 4)
void scores_tri(const f16* Qp, const f16* Xth, float* S) {
    __shared__ alignas(16) f16 smem[8192];
    const int x = blockIdx.x & 7;
    int s = blockIdx.x >> 3;  // 0..259
    int m = 0, n = 0;
#pragma unroll
    for (int q = 7; q >= 0; q--) {
        const int mm = 8 * q + ((q & 1) ? 7 - x : x);
        if (s < mm + 1) { m = mm; n = s; break; }
        s -= mm + 1;
    }
    body64<1>(smem, smem + 4096, Qp, Xth, S, nullptr, nullptr,
              m * 64, n * 64, 4096, 4096, 1024, 1024, 1024);
}

// Narrow GEMMs [M=4096, N=1024], 1024 blocks.
// CAUSAL: m = 8q + (q odd ? 7-x : x), q descending (LPT, uniform residues);
// else m = x + 8q.
template <int MODE, bool CAUSAL_K>
__global__ __launch_bounds__(256, 4)
void gemm_narrow(const f16* __restrict__ A, const f16* __restrict__ B,
                 float* __restrict__ Cf, f16* __restrict__ Ch,
                 const float* __restrict__ resid, int M, int N, int K, int lda) {
    __shared__ alignas(16) f16 smem[8192];
    const int x = blockIdx.x & 7, s = blockIdx.x >> 3;  // s in 0..127
    const int q = 7 - (s >> 4), n = s & 15;
    const int m = CAUSAL_K ? (8 * q + ((q & 1) ? 7 - x : x)) : (x + 8 * q);
    const int m0 = m * 64, n0 = n * 64;
    const int Keff = CAUSAL_K ? (K < m0 + 64 ? K : m0 + 64) : K;
    body64<MODE>(smem, smem + 4096, A, B, Cf, Ch, resid,
                 m0, n0, M, N, K, lda, Keff);
}

// ---------------------------------------------------------------------------
extern "C" void kernel_launch(void* const* d_in, const int* in_sizes, int n_in,
                              void* d_out, int out_size, void* d_ws, size_t ws_size,
                              hipStream_t stream) {
    const int D = 1024, NT = 4096;
    const float* X = (const float*)d_in[0];
    const float* W[6] = {(const float*)d_in[1], (const float*)d_in[2],
                         (const float*)d_in[3], (const float*)d_in[4],
                         (const float*)d_in[5], (const float*)d_in[6]};
    char* ws = (char*)d_ws;
    auto MB = [](size_t x) { return x << 20; };

    // Workspace (144 MB peak):
    float* Xtf  = (float*)(ws + MB(0));    // [NT][D] fp32 residual
    f16*   Xth  = (f16*)(ws + MB(16));     // [NT][D]
    f16*   Wqh  = (f16*)(ws + MB(24));
    f16*   Wkh  = (f16*)(ws + MB(26));
    f16*   Wvh  = (f16*)(ws + MB(28));
    f16*   Wot  = (f16*)(ws + MB(30));
    f16*   W4t  = (f16*)(ws + MB(32));
    f16*   W5t  = (f16*)(ws + MB(34));
    f16*   GT   = (f16*)(ws + MB(36));     // [D][D]
    f16*   HT   = (f16*)(ws + MB(38));     // [D][D]
    f16*   Qp   = (f16*)(ws + MB(40));     // [NT][D] (dead after scores)
    float* S    = (float*)(ws + MB(48));   // [NT][NT] fp32 -> A f16 in-place
    f16*   RHt  = (f16*)(ws + MB(112));    // [D][NT]
    float* Y1f  = (float*)(ws + MB(120));  // [NT][D] fp32
    f16*   Y1h  = (f16*)(ws + MB(136));    // [NT][D]
    f16*   hb   = (f16*)(ws + MB(40));     // over Qp (dead)
    float* outF = (float*)d_out;           // [D][NT]

    // 1. Prep.
    transpose_x<<<dim3(NT / 32, D / 32), 256, 0, stream>>>(X, Xtf, Xth, D, NT);
    prep_w<<<dim3(D / 32, D / 32, 6), 256, 0, stream>>>(
        W[0], W[1], W[2], W[3], W[4], W[5], Wqh, Wkh, Wvh, Wot, W4t, W5t, D);

    // 2. GT = Wk*Wq^T ++ HT = Wo^T*Wv^T.
    tiny_pair<<<512, 256, 0, stream>>>(Wkh, Wqh, GT, Wot, Wvh, HT);

    // 3. Q' = Xt*G ++ RHt = HT*Xt^T.
    mid_pair<<<2048, 256, 0, stream>>>(Xth, GT, Qp, HT, RHt);

    // 4. Scores (lower triangle, fp32).
    scores_tri<<<2080, 256, 0, stream>>>(Qp, Xth, S);

    // 5. Softmax in-place (A f16, pitch 2*NT).
    softmax_causal_inplace<<<NT, 256, 0, stream>>>(S, NT);
    f16* Ab = (f16*)S;

    // 6. Y1 = Xt + A@RH (causal-K truncation, XCD-affine + balanced).
    gemm_narrow<2, true><<<1024, 256, 0, stream>>>(
        Ab, RHt, Y1f, Y1h, Xtf, NT, D, NT, 2 * NT);

    // 7. h = relu(Y1 @ mlp_in).
    gemm_narrow<3, false><<<1024, 256, 0, stream>>>(
        Y1h, W4t, nullptr, hb, nullptr, NT, D, D, D);

    // 8. out = (Y1 + h @ mlp_out)^T.
    gemm_narrow<4, false><<<1024, 256, 0, stream>>>(
        hb, W5t, outF, nullptr, Y1f, NT, D, D, D);
}

// Round 11
// 258.881 us; speedup vs baseline: 2.0709x; 1.0348x over previous
//
#include <hip/hip_runtime.h>
#include <stdint.h>
#include <stddef.h>

using f16 = _Float16;
typedef __attribute__((ext_vector_type(8))) _Float16 f16x8;
typedef __attribute__((ext_vector_type(4))) float f32x4;

// ---------------------------------------------------------------------------
__device__ __forceinline__ void async_copy16(const f16* g, f16* l) {
    __builtin_amdgcn_global_load_lds(
        (const __attribute__((address_space(1))) void*)g,
        (__attribute__((address_space(3))) void*)l, 16, 0, 0);
}

// ---------------------------------------------------------------------------
// Transpose X [D][NT] fp32 -> Xt [NT][D] fp32 + fp16.
__global__ __launch_bounds__(256)
void transpose_x(const float* __restrict__ in, float* __restrict__ outF,
                 f16* __restrict__ outH, int R, int C) {
    __shared__ float tile[32][33];
    const int tx = threadIdx.x & 31, ty = threadIdx.x >> 5;
    const int c0 = blockIdx.x * 32, r0 = blockIdx.y * 32;
#pragma unroll
    for (int j = 0; j < 4; j++)
        tile[ty + j * 8][tx] = in[(size_t)(r0 + ty + j * 8) * C + c0 + tx];
    __syncthreads();
#pragma unroll
    for (int j = 0; j < 4; j++) {
        float v = tile[tx][ty + j * 8];
        size_t idx = (size_t)(c0 + ty + j * 8) * R + r0 + tx;
        outF[idx] = v;
        outH[idx] = (f16)v;
    }
}

// Weight prep: z<3 -> fp16 convert (Wq, Wk, Wv); z>=3 -> fp16 transpose.
__global__ __launch_bounds__(256)
void prep_w(const float* __restrict__ w0, const float* __restrict__ w1,
            const float* __restrict__ w2, const float* __restrict__ w3,
            const float* __restrict__ w4, const float* __restrict__ w5,
            f16* o0, f16* o1, f16* o2, f16* o3, f16* o4, f16* o5, int D) {
    const int z = blockIdx.z;
    const float* in = z == 0 ? w0 : z == 1 ? w1 : z == 2 ? w2 : z == 3 ? w3 : z == 4 ? w4 : w5;
    f16* out = z == 0 ? o0 : z == 1 ? o1 : z == 2 ? o2 : z == 3 ? o3 : z == 4 ? o4 : o5;
    const int tx = threadIdx.x & 31, ty = threadIdx.x >> 5;
    const int c0 = blockIdx.x * 32, r0 = blockIdx.y * 32;
    if (z < 3) {
#pragma unroll
        for (int j = 0; j < 4; j++) {
            size_t idx = (size_t)(r0 + ty + j * 8) * D + c0 + tx;
            out[idx] = (f16)in[idx];
        }
    } else {
        __shared__ float tile[32][33];
#pragma unroll
        for (int j = 0; j < 4; j++)
            tile[ty + j * 8][tx] = in[(size_t)(r0 + ty + j * 8) * D + c0 + tx];
        __syncthreads();
#pragma unroll
        for (int j = 0; j < 4; j++)
            out[(size_t)(c0 + ty + j * 8) * D + r0 + tx] = (f16)tile[tx][ty + j * 8];
    }
}

// ---------------------------------------------------------------------------
// Causal softmax IN-PLACE: fp32 S row -> f16 A in same memory (pitch 2N).
// Zero-fill truncated at lim = ceil128(row+1): the A@RH GEMM reads A cols
// only up to Keff = ceil128(m0+64), and for every row in a 64-block lim
// covers exactly that span.
__global__ __launch_bounds__(256)
void softmax_causal_inplace(float* __restrict__ S, int N) {
    const int row = blockIdx.x;
    const int len = row + 1;
    const int lim = ((row >> 7) + 1) << 7;
    float* s = S + (size_t)row * N;
    f16* a = (f16*)s;
    __shared__ float red[256];
    const int t = threadIdx.x;

    float v[16];
    float mx = -1e30f;
#pragma unroll
    for (int j = 0; j < 16; j++) {
        int c = t + j * 256;
        if (c < len) { v[j] = s[c]; mx = fmaxf(mx, v[j]); }
    }
    red[t] = mx; __syncthreads();
    for (int o = 128; o > 0; o >>= 1) { if (t < o) red[t] = fmaxf(red[t], red[t + o]); __syncthreads(); }
    mx = red[0]; __syncthreads();

    float sum = 0.f;
#pragma unroll
    for (int j = 0; j < 16; j++) {
        int c = t + j * 256;
        if (c < len) sum += __expf(v[j] - mx);
    }
    red[t] = sum; __syncthreads();
    for (int o = 128; o > 0; o >>= 1) { if (t < o) red[t] += red[t + o]; __syncthreads(); }
    const float inv = 1.0f / red[0];
#pragma unroll
    for (int j = 0; j < 16; j++) {
        int c = t + j * 256;
        if (c < lim) a[c] = (f16)((c < len) ? __expf(v[j] - mx) * inv : 0.0f);
    }
}

// ---------------------------------------------------------------------------
// 64x64x128 fp16 GEMM body. global_load_lds staging (proven), BK=128: 4
// stacked k-quarter chunks per operand ([4][64][32], same per-chunk layout
// as R10 -> no new bank conflicts), 8 copies/thread + 16 MFMAs/wave per
// barrier pair — half the drains of BK=64. 32 KB LDS, 4 blocks/CU.
// Keff must be a multiple of 128.
// MODE 0: Ch = f16(acc)
// MODE 1: Cf = acc
// MODE 2: Cf = acc + resid; Ch = f16(Cf)
// MODE 3: Ch = f16(relu(acc))
// MODE 4: Cf[col*M + row] = acc + resid[row*N + col]  (transposed store)
template <int MODE>
__device__ __forceinline__ void body64(
    f16* lA, f16* lB, const f16* __restrict__ A, const f16* __restrict__ B,
    float* __restrict__ Cf, f16* __restrict__ Ch, const float* __restrict__ resid,
    int m0, int n0, int M, int N, int K, int lda, int Keff) {
    const int t = threadIdx.x;
    const int lane = t & 63, wave = t >> 6;
    const int wm = (wave >> 1) * 32, wn = (wave & 1) * 32;
    const int lm = lane & 15, lq = lane >> 4;
    const int sr = t >> 2, sc = (t & 3) * 8;   // 64 rows x 32 cols per chunk

    f32x4 acc[2][2] = {};

    for (int k0 = 0; k0 < Keff; k0 += 128) {
#pragma unroll
        for (int r = 0; r < 4; r++)
            async_copy16(A + (size_t)(m0 + sr) * lda + k0 + r * 32 + sc,
                         lA + r * 2048 + t * 8);
#pragma unroll
        for (int r = 0; r < 4; r++)
            async_copy16(B + (size_t)(n0 + sr) * K + k0 + r * 32 + sc,
                         lB + r * 2048 + t * 8);
        __syncthreads();

#pragma unroll
        for (int kk = 0; kk < 4; kk++) {
            f16x8 af[2], bf[2];
#pragma unroll
            for (int i = 0; i < 2; i++)
                af[i] = *(const f16x8*)&lA[kk * 2048 + (wm + i * 16 + lm) * 32 + lq * 8];
#pragma unroll
            for (int j = 0; j < 2; j++)
                bf[j] = *(const f16x8*)&lB[kk * 2048 + (wn + j * 16 + lm) * 32 + lq * 8];
#pragma unroll
            for (int i = 0; i < 2; i++)
#pragma unroll
                for (int j = 0; j < 2; j++)
                    acc[i][j] = __builtin_amdgcn_mfma_f32_16x16x32_f16(
                        af[i], bf[j], acc[i][j], 0, 0, 0);
        }
        __syncthreads();
    }

    // C/D layout: col = lane&15, row = (lane>>4)*4 + reg.
#pragma unroll
    for (int i = 0; i < 2; i++) {
        const int row = m0 + wm + i * 16 + lq * 4;
#pragma unroll
        for (int j = 0; j < 2; j++) {
            const int col = n0 + wn + j * 16 + lm;
            f32x4 v = acc[i][j];
#pragma unroll
            for (int r = 0; r < 4; r++) {
                if (MODE == 0) {
                    Ch[(size_t)(row + r) * N + col] = (f16)v[r];
                } else if (MODE == 1) {
                    Cf[(size_t)(row + r) * N + col] = v[r];
                } else if (MODE == 2) {
                    float o = v[r] + resid[(size_t)(row + r) * N + col];
                    Cf[(size_t)(row + r) * N + col] = o;
                    Ch[(size_t)(row + r) * N + col] = (f16)o;
                } else if (MODE == 3) {
                    Ch[(size_t)(row + r) * N + col] = (f16)fmaxf(v[r], 0.0f);
                } else {
                    float o = v[r] + resid[(size_t)(row + r) * N + col];
                    Cf[(size_t)col * M + (row + r)] = o;
                }
            }
        }
    }
}

// ---------------------------------------------------------------------------
// Fused: GT = Wk*Wq^T ++ HT = Wo^T*Wv^T, both [1024^3]. 512 blocks.
__global__ __launch_bounds__(256, 4)
void tiny_pair(const f16* Wkh, const f16* Wqh, f16* GT,
               const f16* Wot, const f16* Wvh, f16* HT) {
    __shared__ alignas(16) f16 smem[16384];
    const int b = blockIdx.x;
    if (b < 256)
        body64<0>(smem, smem + 8192, Wkh, Wqh, nullptr, GT, nullptr,
                  (b >> 4) * 64, (b & 15) * 64, 1024, 1024, 1024, 1024, 1024);
    else {
        const int r = b - 256;
        body64<0>(smem, smem + 8192, Wot, Wvh, nullptr, HT, nullptr,
                  (r >> 4) * 64, (r & 15) * 64, 1024, 1024, 1024, 1024, 1024);
    }
}

// Fused: Q' = Xt*GT^T [4096,1024,1024] ++ RHt = HT*Xt^T [1024,4096,1024].
// 2048 blocks. XCD-affinity: blocks sharing an Xt stripe share blockIdx%8.
__global__ __launch_bounds__(256, 4)
void mid_pair(const f16* Xth, const f16* GT, f16* Qp,
              const f16* HT, f16* RHt) {
    __shared__ alignas(16) f16 smem[16384];
    const int x = blockIdx.x & 7;
    int s = blockIdx.x >> 3;  // 0..255
    if (s < 128) {
        const int m = x + 8 * (s >> 4), n = s & 15;  // A-stripe affinity
        body64<0>(smem, smem + 8192, Xth, GT, nullptr, Qp, nullptr,
                  m * 64, n * 64, 4096, 1024, 1024, 1024, 1024);
    } else {
        s -= 128;
        const int n = x + 8 * (s >> 4), m = s & 15;  // B(Xth)-stripe affinity
        body64<0>(smem, smem + 8192, HT, Xth, nullptr, RHt, nullptr,
                  m * 64, n * 64, 1024, 4096, 1024, 1024, 1024);
    }
}

// Scores over lower triangle: S = Q'*Xt^T, fp32 out. 2080 blocks.
// Residue x owns m = 8q + (q odd ? 7-x : x), q=7..0 (largest first) —
// 260 K-steps per residue (uniform) + A-stripe L2 affinity.
__global__ __launch_bounds__(256, 4)
void scores_tri(const f16* Qp, const f16* Xth, float* S) {
    __shared__ alignas(16) f16 smem[16384];
    const int x = blockIdx.x & 7;
    int s = blockIdx.x >> 3;  // 0..259
    int m = 0, n = 0;
#pragma unroll
    for (int q = 7; q >= 0; q--) {
        const int mm = 8 * q + ((q & 1) ? 7 - x : x);
        if (s < mm + 1) { m = mm; n = s; break; }
        s -= mm + 1;
    }
    body64<1>(smem, smem + 8192, Qp, Xth, S, nullptr, nullptr,
              m * 64, n * 64, 4096, 4096, 1024, 1024, 1024);
}

// Narrow GEMMs [M=4096, N=1024], 1024 blocks.
// CAUSAL: m = 8q + (q odd ? 7-x : x), q descending (LPT, uniform residues),
// Keff rounded up to a 128 multiple (A is zero there); else m = x + 8q.
template <int MODE, bool CAUSAL_K>
__global__ __launch_bounds__(256, 4)
void gemm_narrow(const f16* __restrict__ A, const f16* __restrict__ B,
                 float* __restrict__ Cf, f16* __restrict__ Ch,
                 const float* __restrict__ resid, int M, int N, int K, int lda) {
    __shared__ alignas(16) f16 smem[16384];
    const int x = blockIdx.x & 7, s = blockIdx.x >> 3;  // s in 0..127
    const int q = 7 - (s >> 4), n = s & 15;
    const int m = CAUSAL_K ? (8 * q + ((q & 1) ? 7 - x : x)) : (x + 8 * q);
    const int m0 = m * 64, n0 = n * 64;
    int Keff = K;
    if (CAUSAL_K) {
        Keff = ((m0 + 64 + 127) >> 7) << 7;   // ceil128(m0+64)
        if (Keff > K) Keff = K;
    }
    body64<MODE>(smem, smem + 8192, A, B, Cf, Ch, resid,
                 m0, n0, M, N, K, lda, Keff);
}

// ---------------------------------------------------------------------------
extern "C" void kernel_launch(void* const* d_in, const int* in_sizes, int n_in,
                              void* d_out, int out_size, void* d_ws, size_t ws_size,
                              hipStream_t stream) {
    const int D = 1024, NT = 4096;
    const float* X = (const float*)d_in[0];
    const float* W[6] = {(const float*)d_in[1], (const float*)d_in[2],
                         (const float*)d_in[3], (const float*)d_in[4],
                         (const float*)d_in[5], (const float*)d_in[6]};
    char* ws = (char*)d_ws;
    auto MB = [](size_t x) { return x << 20; };

    // Workspace (144 MB peak):
    float* Xtf  = (float*)(ws + MB(0));    // [NT][D] fp32 residual
    f16*   Xth  = (f16*)(ws + MB(16));     // [NT][D]
    f16*   Wqh  = (f16*)(ws + MB(24));
    f16*   Wkh  = (f16*)(ws + MB(26));
    f16*   Wvh  = (f16*)(ws + MB(28));
    f16*   Wot  = (f16*)(ws + MB(30));
    f16*   W4t  = (f16*)(ws + MB(32));
    f16*   W5t  = (f16*)(ws + MB(34));
    f16*   GT   = (f16*)(ws + MB(36));     // [D][D]
    f16*   HT   = (f16*)(ws + MB(38));     // [D][D]
    f16*   Qp   = (f16*)(ws + MB(40));     // [NT][D] (dead after scores)
    float* S    = (float*)(ws + MB(48));   // [NT][NT] fp32 -> A f16 in-place
    f16*   RHt  = (f16*)(ws + MB(112));    // [D][NT]
    float* Y1f  = (float*)(ws + MB(120));  // [NT][D] fp32
    f16*   Y1h  = (f16*)(ws + MB(136));    // [NT][D]
    f16*   hb   = (f16*)(ws + MB(40));     // over Qp (dead)
    float* outF = (float*)d_out;           // [D][NT]

    // 1. Prep.
    transpose_x<<<dim3(NT / 32, D / 32), 256, 0, stream>>>(X, Xtf, Xth, D, NT);
    prep_w<<<dim3(D / 32, D / 32, 6), 256, 0, stream>>>(
        W[0], W[1], W[2], W[3], W[4], W[5], Wqh, Wkh, Wvh, Wot, W4t, W5t, D);

    // 2. GT = Wk*Wq^T ++ HT = Wo^T*Wv^T.
    tiny_pair<<<512, 256, 0, stream>>>(Wkh, Wqh, GT, Wot, Wvh, HT);

    // 3. Q' = Xt*G ++ RHt = HT*Xt^T.
    mid_pair<<<2048, 256, 0, stream>>>(Xth, GT, Qp, HT, RHt);

    // 4. Scores (lower triangle, fp32).
    scores_tri<<<2080, 256, 0, stream>>>(Qp, Xth, S);

    // 5. Softmax in-place (A f16, pitch 2*NT).
    softmax_causal_inplace<<<NT, 256, 0, stream>>>(S, NT);
    f16* Ab = (f16*)S;

    // 6. Y1 = Xt + A@RH (causal-K truncation, XCD-affine + balanced).
    gemm_narrow<2, true><<<1024, 256, 0, stream>>>(
        Ab, RHt, Y1f, Y1h, Xtf, NT, D, NT, 2 * NT);

    // 7. h = relu(Y1 @ mlp_in).
    gemm_narrow<3, false><<<1024, 256, 0, stream>>>(
        Y1h, W4t, nullptr, hb, nullptr, NT, D, D, D);

    // 8. out = (Y1 + h @ mlp_out)^T.
    gemm_narrow<4, false><<<1024, 256, 0, stream>>>(
        hb, W5t, outF, nullptr, Y1f, NT, D, D, D);
}

// Round 12
// 245.501 us; speedup vs baseline: 2.1838x; 1.0545x over previous
//
#include <hip/hip_runtime.h>
#include <stdint.h>
#include <stddef.h>

using f16 = _Float16;
typedef __attribute__((ext_vector_type(8))) _Float16 f16x8;
typedef __attribute__((ext_vector_type(4))) float f32x4;

// ---------------------------------------------------------------------------
__device__ __forceinline__ void async_copy16(const f16* g, f16* l) {
    __builtin_amdgcn_global_load_lds(
        (const __attribute__((address_space(1))) void*)g,
        (__attribute__((address_space(3))) void*)l, 16, 0, 0);
}

// ---------------------------------------------------------------------------
// Merged prep, 1D grid of 10240 blocks:
//   b < 4096  : X [D][NT] fp32 -> Xt [NT][D] fp32 + f16 (32x32 tiles)
//   b >= 4096 : weights; z<3 f16 convert (Wq,Wk,Wv), z>=3 f16 transpose.
__global__ __launch_bounds__(256)
void prep_all(const float* __restrict__ X, float* __restrict__ Xtf,
              f16* __restrict__ Xth,
              const float* __restrict__ w0, const float* __restrict__ w1,
              const float* __restrict__ w2, const float* __restrict__ w3,
              const float* __restrict__ w4, const float* __restrict__ w5,
              f16* o0, f16* o1, f16* o2, f16* o3, f16* o4, f16* o5,
              int D, int NT) {
    __shared__ float tile[32][33];
    const int tx = threadIdx.x & 31, ty = threadIdx.x >> 5;
    int b = blockIdx.x;
    if (b < 4096) {
        const int c0 = (b & 127) * 32, r0 = (b >> 7) * 32;  // c over NT, r over D
#pragma unroll
        for (int j = 0; j < 4; j++)
            tile[ty + j * 8][tx] = X[(size_t)(r0 + ty + j * 8) * NT + c0 + tx];
        __syncthreads();
#pragma unroll
        for (int j = 0; j < 4; j++) {
            float v = tile[tx][ty + j * 8];
            size_t idx = (size_t)(c0 + ty + j * 8) * D + r0 + tx;
            Xtf[idx] = v;
            Xth[idx] = (f16)v;
        }
        return;
    }
    b -= 4096;
    const int z = b >> 10, r = b & 1023;
    const float* in = z == 0 ? w0 : z == 1 ? w1 : z == 2 ? w2 : z == 3 ? w3 : z == 4 ? w4 : w5;
    f16* out = z == 0 ? o0 : z == 1 ? o1 : z == 2 ? o2 : z == 3 ? o3 : z == 4 ? o4 : o5;
    const int c0 = (r & 31) * 32, r0 = (r >> 5) * 32;
    if (z < 3) {
#pragma unroll
        for (int j = 0; j < 4; j++) {
            size_t idx = (size_t)(r0 + ty + j * 8) * D + c0 + tx;
            out[idx] = (f16)in[idx];
        }
    } else {
#pragma unroll
        for (int j = 0; j < 4; j++)
            tile[ty + j * 8][tx] = in[(size_t)(r0 + ty + j * 8) * D + c0 + tx];
        __syncthreads();
#pragma unroll
        for (int j = 0; j < 4; j++)
            out[(size_t)(c0 + ty + j * 8) * D + r0 + tx] = (f16)tile[tx][ty + j * 8];
    }
}

// ---------------------------------------------------------------------------
// Causal softmax over f16 A rows IN-PLACE (pitch N). Vectorized f16x8,
// single exp pass. Zero-fill to lim = ceil128(row+1) — exactly the span the
// A@RH GEMM reads (Keff = ceil128(m0+64) == lim for every row in the block).
__global__ __launch_bounds__(256)
void softmax_rows(f16* __restrict__ A, int N) {
    const int row = blockIdx.x, len = row + 1;
    const int lim = ((row >> 7) + 1) << 7;
    f16* a = A + (size_t)row * N;
    __shared__ float red[256];
    const int t = threadIdx.x;

    float v[16];
    float mx = -1e30f;
#pragma unroll
    for (int j = 0; j < 2; j++) {
        const int c = (t + j * 256) * 8;
        if (c < len) {
            f16x8 x = *(const f16x8*)(a + c);
#pragma unroll
            for (int e = 0; e < 8; e++) {
                float f = (c + e < len) ? (float)x[e] : -1e30f;
                v[j * 8 + e] = f;
                mx = fmaxf(mx, f);
            }
        } else {
#pragma unroll
            for (int e = 0; e < 8; e++) v[j * 8 + e] = -1e30f;
        }
    }
    red[t] = mx; __syncthreads();
    for (int o = 128; o > 0; o >>= 1) { if (t < o) red[t] = fmaxf(red[t], red[t + o]); __syncthreads(); }
    mx = red[0]; __syncthreads();

    float sum = 0.f;
#pragma unroll
    for (int k = 0; k < 16; k++) {
        float e = (v[k] > -1e29f) ? __expf(v[k] - mx) : 0.0f;
        v[k] = e;
        sum += e;
    }
    red[t] = sum; __syncthreads();
    for (int o = 128; o > 0; o >>= 1) { if (t < o) red[t] += red[t + o]; __syncthreads(); }
    const float inv = 1.0f / red[0];
#pragma unroll
    for (int j = 0; j < 2; j++) {
        const int c = (t + j * 256) * 8;
        if (c < lim) {
            f16x8 o8;
#pragma unroll
            for (int e = 0; e < 8; e++) o8[e] = (f16)(v[j * 8 + e] * inv);
            *(f16x8*)(a + c) = o8;
        }
    }
}

// ---------------------------------------------------------------------------
// 64x64x128 fp16 GEMM body (R11-proven). global_load_lds staging, 4 stacked
// k-quarter chunks per operand [4][64][32]; 32 KB LDS, 4 blocks/CU.
// Keff must be a multiple of 128.
// MODE 0: Ch = f16(acc)
// MODE 1: Cf = acc
// MODE 2: Cf = acc + resid; Ch = f16(Cf)
// MODE 3: Ch = f16(relu(acc))
// MODE 4: Cf[col*M + row] = acc + resid[row*N + col]  (transposed store)
template <int MODE>
__device__ __forceinline__ void body64(
    f16* lA, f16* lB, const f16* __restrict__ A, const f16* __restrict__ B,
    float* __restrict__ Cf, f16* __restrict__ Ch, const float* __restrict__ resid,
    int m0, int n0, int M, int N, int K, int lda, int Keff) {
    const int t = threadIdx.x;
    const int lane = t & 63, wave = t >> 6;
    const int wm = (wave >> 1) * 32, wn = (wave & 1) * 32;
    const int lm = lane & 15, lq = lane >> 4;
    const int sr = t >> 2, sc = (t & 3) * 8;

    f32x4 acc[2][2] = {};

    for (int k0 = 0; k0 < Keff; k0 += 128) {
#pragma unroll
        for (int r = 0; r < 4; r++)
            async_copy16(A + (size_t)(m0 + sr) * lda + k0 + r * 32 + sc,
                         lA + r * 2048 + t * 8);
#pragma unroll
        for (int r = 0; r < 4; r++)
            async_copy16(B + (size_t)(n0 + sr) * K + k0 + r * 32 + sc,
                         lB + r * 2048 + t * 8);
        __syncthreads();

#pragma unroll
        for (int kk = 0; kk < 4; kk++) {
            f16x8 af[2], bf[2];
#pragma unroll
            for (int i = 0; i < 2; i++)
                af[i] = *(const f16x8*)&lA[kk * 2048 + (wm + i * 16 + lm) * 32 + lq * 8];
#pragma unroll
            for (int j = 0; j < 2; j++)
                bf[j] = *(const f16x8*)&lB[kk * 2048 + (wn + j * 16 + lm) * 32 + lq * 8];
#pragma unroll
            for (int i = 0; i < 2; i++)
#pragma unroll
                for (int j = 0; j < 2; j++)
                    acc[i][j] = __builtin_amdgcn_mfma_f32_16x16x32_f16(
                        af[i], bf[j], acc[i][j], 0, 0, 0);
        }
        __syncthreads();
    }

    // C/D layout: col = lane&15, row = (lane>>4)*4 + reg.
#pragma unroll
    for (int i = 0; i < 2; i++) {
        const int row = m0 + wm + i * 16 + lq * 4;
#pragma unroll
        for (int j = 0; j < 2; j++) {
            const int col = n0 + wn + j * 16 + lm;
            f32x4 v = acc[i][j];
#pragma unroll
            for (int r = 0; r < 4; r++) {
                if (MODE == 0) {
                    Ch[(size_t)(row + r) * N + col] = (f16)v[r];
                } else if (MODE == 1) {
                    Cf[(size_t)(row + r) * N + col] = v[r];
                } else if (MODE == 2) {
                    float o = v[r] + resid[(size_t)(row + r) * N + col];
                    Cf[(size_t)(row + r) * N + col] = o;
                    Ch[(size_t)(row + r) * N + col] = (f16)o;
                } else if (MODE == 3) {
                    Ch[(size_t)(row + r) * N + col] = (f16)fmaxf(v[r], 0.0f);
                } else {
                    float o = v[r] + resid[(size_t)(row + r) * N + col];
                    Cf[(size_t)col * M + (row + r)] = o;
                }
            }
        }
    }
}

// ---------------------------------------------------------------------------
// Fused: GT = Wk*Wq^T ++ HT = Wo^T*Wv^T, both [1024^3]. 512 blocks.
__global__ __launch_bounds__(256, 4)
void tiny_pair(const f16* Wkh, const f16* Wqh, f16* GT,
               const f16* Wot, const f16* Wvh, f16* HT) {
    __shared__ alignas(16) f16 smem[16384];
    const int b = blockIdx.x;
    if (b < 256)
        body64<0>(smem, smem + 8192, Wkh, Wqh, nullptr, GT, nullptr,
                  (b >> 4) * 64, (b & 15) * 64, 1024, 1024, 1024, 1024, 1024);
    else {
        const int r = b - 256;
        body64<0>(smem, smem + 8192, Wot, Wvh, nullptr, HT, nullptr,
                  (r >> 4) * 64, (r & 15) * 64, 1024, 1024, 1024, 1024, 1024);
    }
}

// Fused: Q' = Xt*GT^T [4096,1024,1024] ++ RHt = HT*Xt^T [1024,4096,1024].
// 2048 blocks. XCD-affinity: blocks sharing an Xt stripe share blockIdx%8.
__global__ __launch_bounds__(256, 4)
void mid_pair(const f16* Xth, const f16* GT, f16* Qp,
              const f16* HT, f16* RHt) {
    __shared__ alignas(16) f16 smem[16384];
    const int x = blockIdx.x & 7;
    int s = blockIdx.x >> 3;  // 0..255
    if (s < 128) {
        const int m = x + 8 * (s >> 4), n = s & 15;  // A-stripe affinity
        body64<0>(smem, smem + 8192, Xth, GT, nullptr, Qp, nullptr,
                  m * 64, n * 64, 4096, 1024, 1024, 1024, 1024);
    } else {
        s -= 128;
        const int n = x + 8 * (s >> 4), m = s & 15;  // B(Xth)-stripe affinity
        body64<0>(smem, smem + 8192, HT, Xth, nullptr, RHt, nullptr,
                  m * 64, n * 64, 1024, 4096, 1024, 1024, 1024);
    }
}

// Scores over lower triangle, f16 out (A buffer, pitch NT). 2080 blocks.
// Residue x owns m = 8q + (q odd ? 7-x : x), q=7..0 — 260 K-steps per
// residue (uniform) + A-stripe L2 affinity.
__global__ __launch_bounds__(256, 4)
void scores_tri(const f16* Qp, const f16* Xth, f16* Af) {
    __shared__ alignas(16) f16 smem[16384];
    const int x = blockIdx.x & 7;
    int s = blockIdx.x >> 3;  // 0..259
    int m = 0, n = 0;
#pragma unroll
    for (int q = 7; q >= 0; q--) {
        const int mm = 8 * q + ((q & 1) ? 7 - x : x);
        if (s < mm + 1) { m = mm; n = s; break; }
        s -= mm + 1;
    }
    body64<0>(smem, smem + 8192, Qp, Xth, nullptr, Af, nullptr,
              m * 64, n * 64, 4096, 4096, 1024, 1024, 1024);
}

// Narrow GEMMs [M=4096, N=1024], 1024 blocks.
// CAUSAL: m = 8q + (q odd ? 7-x : x), q descending (LPT, uniform residues),
// Keff = ceil128(m0+64); else m = x + 8q.
template <int MODE, bool CAUSAL_K>
__global__ __launch_bounds__(256, 4)
void gemm_narrow(const f16* __restrict__ A, const f16* __restrict__ B,
                 float* __restrict__ Cf, f16* __restrict__ Ch,
                 const float* __restrict__ resid, int M, int N, int K, int lda) {
    __shared__ alignas(16) f16 smem[16384];
    const int x = blockIdx.x & 7, s = blockIdx.x >> 3;  // s in 0..127
    const int q = 7 - (s >> 4), n = s & 15;
    const int m = CAUSAL_K ? (8 * q + ((q & 1) ? 7 - x : x)) : (x + 8 * q);
    const int m0 = m * 64, n0 = n * 64;
    int Keff = K;
    if (CAUSAL_K) {
        Keff = ((m0 + 64 + 127) >> 7) << 7;
        if (Keff > K) Keff = K;
    }
    body64<MODE>(smem, smem + 8192, A, B, Cf, Ch, resid,
                 m0, n0, M, N, K, lda, Keff);
}

// ---------------------------------------------------------------------------
extern "C" void kernel_launch(void* const* d_in, const int* in_sizes, int n_in,
                              void* d_out, int out_size, void* d_ws, size_t ws_size,
                              hipStream_t stream) {
    const int D = 1024, NT = 4096;
    const float* X = (const float*)d_in[0];
    const float* W[6] = {(const float*)d_in[1], (const float*)d_in[2],
                         (const float*)d_in[3], (const float*)d_in[4],
                         (const float*)d_in[5], (const float*)d_in[6]};
    char* ws = (char*)d_ws;
    auto MB = [](size_t x) { return x << 20; };

    // Workspace (112 MB peak):
    float* Xtf  = (float*)(ws + MB(0));    // [NT][D] fp32 residual
    f16*   Xth  = (f16*)(ws + MB(16));     // [NT][D]
    f16*   Wqh  = (f16*)(ws + MB(24));
    f16*   Wkh  = (f16*)(ws + MB(26));
    f16*   Wvh  = (f16*)(ws + MB(28));
    f16*   Wot  = (f16*)(ws + MB(30));
    f16*   W4t  = (f16*)(ws + MB(32));
    f16*   W5t  = (f16*)(ws + MB(34));
    f16*   GT   = (f16*)(ws + MB(36));     // [D][D]
    f16*   HT   = (f16*)(ws + MB(38));     // [D][D]
    f16*   Qp   = (f16*)(ws + MB(40));     // [NT][D] (dead after scores)
    f16*   Af   = (f16*)(ws + MB(48));     // [NT][NT] f16 scores -> softmax A
    f16*   RHt  = (f16*)(ws + MB(80));     // [D][NT]
    float* Y1f  = (float*)(ws + MB(88));   // [NT][D] fp32
    f16*   Y1h  = (f16*)(ws + MB(104));    // [NT][D]
    f16*   hb   = (f16*)(ws + MB(40));     // over Qp (dead)
    float* outF = (float*)d_out;           // [D][NT]

    // 1. Prep (merged).
    prep_all<<<10240, 256, 0, stream>>>(X, Xtf, Xth, W[0], W[1], W[2], W[3],
                                        W[4], W[5], Wqh, Wkh, Wvh, Wot, W4t,
                                        W5t, D, NT);

    // 2. GT = Wk*Wq^T ++ HT = Wo^T*Wv^T.
    tiny_pair<<<512, 256, 0, stream>>>(Wkh, Wqh, GT, Wot, Wvh, HT);

    // 3. Q' = Xt*G ++ RHt = HT*Xt^T.
    mid_pair<<<2048, 256, 0, stream>>>(Xth, GT, Qp, HT, RHt);

    // 4. Scores (lower triangle, f16 out).
    scores_tri<<<2080, 256, 0, stream>>>(Qp, Xth, Af);

    // 5. Softmax in-place on f16 A (pitch NT).
    softmax_rows<<<NT, 256, 0, stream>>>(Af, NT);

    // 6. Y1 = Xt + A@RH (causal-K truncation, XCD-affine + balanced).
    gemm_narrow<2, true><<<1024, 256, 0, stream>>>(
        Af, RHt, Y1f, Y1h, Xtf, NT, D, NT, NT);

    // 7. h = relu(Y1 @ mlp_in).
    gemm_narrow<3, false><<<1024, 256, 0, stream>>>(
        Y1h, W4t, nullptr, hb, nullptr, NT, D, D, D);

    // 8. out = (Y1 + h @ mlp_out)^T.
    gemm_narrow<4, false><<<1024, 256, 0, stream>>>(
        hb, W5t, outF, nullptr, Y1f, NT, D, D, D);
}